// Round 6
// baseline (105.285 us; speedup 1.0000x reference)
//
#include <hip/hip_runtime.h>

#define D 128
#define NT2 2080            // 64*65/2 upper-triangular 128x128 super-tiles
#define NPART 8320          // NT2 * 4 quadrant partials

typedef __attribute__((ext_vector_type(8))) short short8;   // 8 x bf16 (4 VGPRs)
typedef __attribute__((ext_vector_type(4))) float float4v;  // 4 x f32 acc
typedef __attribute__((ext_vector_type(2))) float float2v;  // 2 x f32 (v_pk_* ops)

static __device__ __forceinline__ unsigned short f2bf(float f) {
    unsigned int u = __float_as_uint(f);
    unsigned int r = (u + 0x7fffu + ((u >> 16) & 1u)) >> 16;  // RNE
    return (unsigned short)r;
}

// async global->LDS, 16B per lane; lds dest must be wave-uniform base + lane*16
static __device__ __forceinline__ void gld16(const void* g, void* l) {
    __builtin_amdgcn_global_load_lds(
        (const __attribute__((address_space(1))) unsigned int*)g,
        (__attribute__((address_space(3))) unsigned int*)l, 16, 0, 0);
}

// ws float-index layout:
//   [0..8)           (scratch)            ZEROED by memset node
//   [8..40)          ss32[32] (f32)       ZEROED; k_prep atomicAdd rowsq block-sums
//   [64..192)        colsum[128] (f32)    ZEROED; k_prep atomicAdd column sums
//   [33280..41471]   rowsq[8192]          k_prep plain stores
//   [41472..49792)   partial[8320]        mmd_main plain stores (every slot written)
//   [65536..589824)  XT: bf16 X, FRAGMENT-MAJOR tiled (2 MB)
//                    8-bf16 chunk c of row r -> uint4 idx (r>>4)*256 + c*16 + (r&15)
//                    => 128-row super-panel p is 32KB contiguous at uint4 idx p*2048

// ---- P1+P2 fused (proven round-4/5 version, unchanged) ----
__global__ __launch_bounds__(256) void k_prep(const float* __restrict__ src,
                                              const float* __restrict__ tgt,
                                              float* __restrict__ wsf,
                                              unsigned int* __restrict__ XTu) {
    __shared__ float shs[4];
    __shared__ float cp[2][128];
    if (blockIdx.x < 2048) {
        float* rowsq = wsf + 33280;
        const int wv = threadIdx.x >> 6, lane = threadIdx.x & 63;
        const int gr = blockIdx.x * 4 + wv;
        const float* Xr = (gr < 4096) ? src + (size_t)gr * D : tgt + (size_t)(gr - 4096) * D;
        float2 f = ((const float2*)Xr)[lane];
        XTu[(gr >> 4) * 1024 + (lane >> 2) * 64 + (gr & 15) * 4 + (lane & 3)] =
            (unsigned)f2bf(f.x) | ((unsigned)f2bf(f.y) << 16);
        float s = f.x * f.x + f.y * f.y;
        #pragma unroll
        for (int off = 32; off; off >>= 1) s += __shfl_down(s, off);
        if (lane == 0) { rowsq[gr] = s; shs[wv] = s; }
        __syncthreads();
        if (threadIdx.x == 0)
            atomicAdd(wsf + 8 + (blockIdx.x & 31), (shs[0] + shs[1]) + (shs[2] + shs[3]));
    } else {
        int b = blockIdx.x - 2048;
        int col = threadIdx.x & 127, half = threadIdx.x >> 7;
        const float* X = (b < 64) ? src + (size_t)(b * 64) * D
                                  : tgt + (size_t)((b - 64) * 64) * D;
        float p0 = 0.f, p1 = 0.f, p2 = 0.f, p3 = 0.f;
        #pragma unroll 4
        for (int i = 0; i < 32; i += 4) {
            p0 += X[(size_t)(2 * (i + 0) + half) * D + col];
            p1 += X[(size_t)(2 * (i + 1) + half) * D + col];
            p2 += X[(size_t)(2 * (i + 2) + half) * D + col];
            p3 += X[(size_t)(2 * (i + 3) + half) * D + col];
        }
        cp[half][col] = (p0 + p1) + (p2 + p3);
        __syncthreads();
        if (threadIdx.x < 128)
            atomicAdd(wsf + 64 + threadIdx.x, cp[0][threadIdx.x] + cp[1][threadIdx.x]);
    }
}

// ---- M: one 128x128 super-tile per 4-wave block. A panel (32 KB) staged once
//      in LDS, shared by waves; each wave's B-half (16 KB) read DIRECT from L2
//      (1 KB contiguous b128 chunks, L1-friendly: 2 waves share each half).
//      LDS 32 KB + launch_bounds(256,4) -> 4 blocks/CU, 16 waves/CU: double
//      round-2's latency-hiding depth. One barrier per block; plain-store tail.
__global__ __launch_bounds__(256, 4) void mmd_main(const uint4* __restrict__ XT,
                                                   const float* __restrict__ wsf,
                                                   float* __restrict__ partial) {
    __shared__ uint4 Alds[2048];   // 32 KB A panel only
    const float* rowsq = wsf + 33280;
    const int tid = threadIdx.x;
    const int lane = tid & 63, wv = tid >> 6;
    const int quad = lane >> 4, mrow = lane & 15;
    const int wm = wv >> 1, wn = wv & 1;             // quadrant of the super-tile

    // ---- per-wave redundant c4 (3 vector loads + shuffles; L2-resident) ----
    float c4;
    {
        const float* colsum = wsf + 64;
        const float* ss32 = wsf + 8;
        float cA = colsum[lane], cB = colsum[64 + lane];
        float sq = cA * cA + cB * cB;                // -> sum of colsum^2
        float sv = (lane < 32) ? ss32[lane] : 0.f;   // -> sum of rowsq
        #pragma unroll
        for (int off = 32; off; off >>= 1) {
            sq += __shfl_down(sq, off);
            sv += __shfl_down(sv, off);
        }
        double sumL2 = 2.0 * 8192.0 * (double)sv - 2.0 * (double)sq;
        double bw = sumL2 / (8192.0 * 8192.0 - 8192.0) / 4.0;   // /KERNEL_MUL^(5/2)
        float c4l = (float)(-1.4426950408889634 / (bw * 16.0));
        c4 = __shfl(c4l, 0);
    }

    // XCD-aware swizzle (2080 % 8 == 0 -> bijective): contiguous t2 chunk per XCD
    int b = blockIdx.x;
    int t2 = (b & 7) * (NT2 / 8) + (b >> 3);

    // t2 -> (pi <= pj) over 64 super-panels; base(p) = p*(129-p)/2
    int pi = (int)((129.0 - sqrt(129.0 * 129.0 - 8.0 * (double)t2)) * 0.5);
    auto base = [](int p) { return (p * (129 - p)) >> 1; };
    while (base(pi + 1) <= t2) ++pi;
    while (base(pi) > t2) --pi;
    int pj = pi + (t2 - base(pi));

    // stage A panel: 32KB contiguous; 256 thr x 16B = 4KB per issue
    const char* gA = (const char*)(XT + (size_t)pi * 2048);
    char* lA = (char*)Alds;
    #pragma unroll
    for (int it = 0; it < 8; ++it)
        gld16(gA + it * 4096 + tid * 16, lA + it * 4096 + tid * 16);

    const uint4* As = Alds + wm * 1024;                          // 64-row half
    const uint4* Bg = XT + (size_t)pj * 2048 + wn * 1024;        // B half, global
    const int ti = pi * 2 + wm, tj = pj * 2 + wn;                // 64-row tiles
    __syncthreads();   // drains vmcnt (global_load_lds) before ds_reads

    float4v acc[4][4];
    #pragma unroll
    for (int mt = 0; mt < 4; ++mt)
        #pragma unroll
        for (int nt = 0; nt < 4; ++nt)
            acc[mt][nt] = (float4v){0.f, 0.f, 0.f, 0.f};

    #pragma unroll
    for (int kc = 0; kc < 4; ++kc) {
        short8 af[4], bf[4];
        #pragma unroll
        for (int mt = 0; mt < 4; ++mt)
            af[mt] = *(const short8*)&As[mt * 256 + kc * 64 + lane];
        #pragma unroll
        for (int nt = 0; nt < 4; ++nt)
            bf[nt] = *(const short8*)&Bg[nt * 256 + kc * 64 + lane];   // direct L2
        #pragma unroll
        for (int mt = 0; mt < 4; ++mt)
            #pragma unroll
            for (int nt = 0; nt < 4; ++nt)
                acc[mt][nt] = __builtin_amdgcn_mfma_f32_16x16x32_bf16(af[mt], bf[nt], acc[mt][nt], 0, 0, 0);
    }

    // epilogue: e = exp2(pk_fma(d, -2c4, rA*c4 + rB*c4)); sum e^{1,2,4,8,16}
    const float* rsqA = rowsq + ti * 64;
    const float* rsqB = rowsq + tj * 64;
    const float cm2 = -2.f * c4;
    const float2v cm2v = {cm2, cm2};
    float2v part2 = {0.f, 0.f};
    #pragma unroll
    for (int mt = 0; mt < 4; ++mt) {
        const float2v rA01 = { rsqA[mt * 16 + quad * 4 + 0] * c4,
                               rsqA[mt * 16 + quad * 4 + 1] * c4 };
        const float2v rA23 = { rsqA[mt * 16 + quad * 4 + 2] * c4,
                               rsqA[mt * 16 + quad * 4 + 3] * c4 };
        #pragma unroll
        for (int nt = 0; nt < 4; ++nt) {
            float rBc = rsqB[nt * 16 + mrow] * c4;
            const float2v rB2 = {rBc, rBc};
            float4v d = acc[mt][nt];
            float2v d01 = {d[0], d[1]}, d23 = {d[2], d[3]};
            float2v a01 = d01 * cm2v + (rA01 + rB2);   // v_pk_fma + v_pk_add
            float2v a23 = d23 * cm2v + (rA23 + rB2);
            float2v e1a = { __builtin_amdgcn_exp2f(a01[0]), __builtin_amdgcn_exp2f(a01[1]) };
            float2v e1b = { __builtin_amdgcn_exp2f(a23[0]), __builtin_amdgcn_exp2f(a23[1]) };
            float2v e2a = e1a * e1a, e4a = e2a * e2a, e8a = e4a * e4a, e16a = e8a * e8a;
            float2v e2b = e1b * e1b, e4b = e2b * e2b, e8b = e4b * e4b, e16b = e8b * e8b;
            part2 += (e1a + e2a) + ((e4a + e8a) + e16a);
            part2 += (e1b + e2b) + ((e4b + e8b) + e16b);
        }
    }
    float part = part2[0] + part2[1];
    #pragma unroll
    for (int off = 32; off; off >>= 1) part += __shfl_down(part, off);

    if (lane == 0) {
        float wgt;
        if (pi == pj) {
            if (wm == 1 && wn == 0) wgt = 0.f;        // duplicate quadrant
            else wgt = (ti == tj) ? 1.f : 2.f;
        } else {
            wgt = ((pi < 32) == (pj < 32)) ? 2.f : -2.f;
        }
        partial[t2 * 4 + wv] = wgt * part;
    }
}

// ---- F: reduce per-quadrant partials in fp64 (independent chains), scale, emit ----
__global__ __launch_bounds__(256) void f_final(const float* __restrict__ wsf,
                                               float* __restrict__ out) {
    const float* partial = wsf + 41472;
    int tid = threadIdx.x, lane = tid & 63;
    double a0 = 0.0, a1 = 0.0, a2 = 0.0, a3 = 0.0;
    #pragma unroll 4
    for (int i = tid; i < NPART; i += 1024) {
        a0 += (double)partial[i];
        if (i + 256 < NPART) a1 += (double)partial[i + 256];
        if (i + 512 < NPART) a2 += (double)partial[i + 512];
        if (i + 768 < NPART) a3 += (double)partial[i + 768];
    }
    double s = (a0 + a1) + (a2 + a3);
    #pragma unroll
    for (int off = 32; off; off >>= 1) s += __shfl_down(s, off);
    __shared__ double r4[4];
    if (lane == 0) r4[tid >> 6] = s;
    __syncthreads();
    if (tid == 0)
        out[0] = (float)(((r4[0] + r4[1]) + (r4[2] + r4[3])) * (1.0 / (4096.0 * 4096.0)));
}

extern "C" void kernel_launch(void* const* d_in, const int* in_sizes, int n_in,
                              void* d_out, int out_size, void* d_ws, size_t ws_size,
                              hipStream_t stream) {
    const float* src = (const float*)d_in[0];
    const float* tgt = (const float*)d_in[1];
    float* wsf = (float*)d_ws;
    unsigned int* XTu = (unsigned int*)(wsf + 65536);   // byte 256K, 2 MB tiled bf16
    float* partial = wsf + 41472;

    hipMemsetAsync(wsf, 0, 1024, stream);   // ss32 + colsum scratch for c4
    hipLaunchKernelGGL(k_prep, dim3(2176), dim3(256), 0, stream, src, tgt, wsf, XTu);
    hipLaunchKernelGGL(mmd_main, dim3(NT2), dim3(256), 0, stream,
                       (const uint4*)XTu, wsf, partial);
    hipLaunchKernelGGL(f_final, dim3(1), dim3(256), 0, stream, wsf, (float*)d_out);
}

// Round 7
// 102.073 us; speedup vs baseline: 1.0315x; 1.0315x over previous
//
#include <hip/hip_runtime.h>

#define D 128
#define NT2 2080            // 64*65/2 upper-triangular 128x128 super-tiles

typedef __attribute__((ext_vector_type(8))) short short8;   // 8 x bf16 (4 VGPRs)
typedef __attribute__((ext_vector_type(4))) float float4v;  // 4 x f32 acc
typedef __attribute__((ext_vector_type(2))) float float2v;  // 2 x f32 (v_pk_* ops)

static __device__ __forceinline__ unsigned short f2bf(float f) {
    unsigned int u = __float_as_uint(f);
    unsigned int r = (u + 0x7fffu + ((u >> 16) & 1u)) >> 16;  // RNE
    return (unsigned short)r;
}

// async global->LDS, 16B per lane; lds dest must be wave-uniform base + lane*16
static __device__ __forceinline__ void gld16(const void* g, void* l) {
    __builtin_amdgcn_global_load_lds(
        (const __attribute__((address_space(1))) unsigned int*)g,
        (__attribute__((address_space(3))) unsigned int*)l, 16, 0, 0);
}

// ws float-index layout:
//   [0..8)           (scratch)            ZEROED by memset node
//   [8..40)          ss32[32] (f32)       ZEROED; k_prep atomicAdd rowsq block-sums
//   [64..192)        colsum[128] (f32)    ZEROED; k_prep atomicAdd column sums
//   [192..256)       acc32[32] (f64)      ZEROED; mmd_main non-returning f64 adds
//   [33280..41471]   rowsq[8192]          k_prep plain stores
//   [65536..589824)  XT: bf16 X, FRAGMENT-MAJOR tiled (2 MB)
//                    8-bf16 chunk c of row r -> uint4 idx (r>>4)*256 + c*16 + (r&15)
//                    => 128-row super-panel p is 32KB contiguous at uint4 idx p*2048

// ---- P1+P2 fused (proven round-4/5/6 version, unchanged) ----
__global__ __launch_bounds__(256) void k_prep(const float* __restrict__ src,
                                              const float* __restrict__ tgt,
                                              float* __restrict__ wsf,
                                              unsigned int* __restrict__ XTu) {
    __shared__ float shs[4];
    __shared__ float cp[2][128];
    if (blockIdx.x < 2048) {
        float* rowsq = wsf + 33280;
        const int wv = threadIdx.x >> 6, lane = threadIdx.x & 63;
        const int gr = blockIdx.x * 4 + wv;
        const float* Xr = (gr < 4096) ? src + (size_t)gr * D : tgt + (size_t)(gr - 4096) * D;
        float2 f = ((const float2*)Xr)[lane];
        XTu[(gr >> 4) * 1024 + (lane >> 2) * 64 + (gr & 15) * 4 + (lane & 3)] =
            (unsigned)f2bf(f.x) | ((unsigned)f2bf(f.y) << 16);
        float s = f.x * f.x + f.y * f.y;
        #pragma unroll
        for (int off = 32; off; off >>= 1) s += __shfl_down(s, off);
        if (lane == 0) { rowsq[gr] = s; shs[wv] = s; }
        __syncthreads();
        if (threadIdx.x == 0)
            atomicAdd(wsf + 8 + (blockIdx.x & 31), (shs[0] + shs[1]) + (shs[2] + shs[3]));
    } else {
        int b = blockIdx.x - 2048;
        int col = threadIdx.x & 127, half = threadIdx.x >> 7;
        const float* X = (b < 64) ? src + (size_t)(b * 64) * D
                                  : tgt + (size_t)((b - 64) * 64) * D;
        float p0 = 0.f, p1 = 0.f, p2 = 0.f, p3 = 0.f;
        #pragma unroll 4
        for (int i = 0; i < 32; i += 4) {
            p0 += X[(size_t)(2 * (i + 0) + half) * D + col];
            p1 += X[(size_t)(2 * (i + 1) + half) * D + col];
            p2 += X[(size_t)(2 * (i + 2) + half) * D + col];
            p3 += X[(size_t)(2 * (i + 3) + half) * D + col];
        }
        cp[half][col] = (p0 + p1) + (p2 + p3);
        __syncthreads();
        if (threadIdx.x < 128)
            atomicAdd(wsf + 64 + threadIdx.x, cp[0][threadIdx.x] + cp[1][threadIdx.x]);
    }
}

// ---- M: round-2's proven core VERBATIM (one 128x128 super-tile per 4-wave
//      block, both panels staged via global_load_lds, 64KB LDS, 2 blocks/CU,
//      default launch bounds). Only the c4 source (prologue, proven R4) and
//      the tail (non-returning f64 atomic, proven R5) differ. ----
__global__ __launch_bounds__(256) void mmd_main(const uint4* __restrict__ XT,
                                                float* __restrict__ wsf) {
    __shared__ uint4 lds[4096];   // 64 KB: A panel [0,2048), B panel [2048,4096)
    __shared__ float fpart[4];
    const float* rowsq = wsf + 33280;
    const int tid = threadIdx.x;
    const int lane = tid & 63, wv = tid >> 6;
    const int quad = lane >> 4, mrow = lane & 15;
    const int wm = wv >> 1, wn = wv & 1;             // quadrant of the super-tile

    // ---- per-wave redundant c4 (3 vector loads + shuffles; L2-resident) ----
    float c4;
    {
        const float* colsum = wsf + 64;
        const float* ss32 = wsf + 8;
        float cA = colsum[lane], cB = colsum[64 + lane];
        float sq = cA * cA + cB * cB;                // -> sum of colsum^2
        float sv = (lane < 32) ? ss32[lane] : 0.f;   // -> sum of rowsq
        #pragma unroll
        for (int off = 32; off; off >>= 1) {
            sq += __shfl_down(sq, off);
            sv += __shfl_down(sv, off);
        }
        double sumL2 = 2.0 * 8192.0 * (double)sv - 2.0 * (double)sq;
        double bw = sumL2 / (8192.0 * 8192.0 - 8192.0) / 4.0;   // /KERNEL_MUL^(5/2)
        float c4l = (float)(-1.4426950408889634 / (bw * 16.0));
        c4 = __shfl(c4l, 0);
    }

    // XCD-aware swizzle (2080 % 8 == 0 -> bijective): contiguous t2 chunk per XCD
    int b = blockIdx.x;
    int t2 = (b & 7) * (NT2 / 8) + (b >> 3);

    // t2 -> (pi <= pj) over 64 super-panels; base(p) = p*(129-p)/2
    int pi = (int)((129.0 - sqrt(129.0 * 129.0 - 8.0 * (double)t2)) * 0.5);
    auto base = [](int p) { return (p * (129 - p)) >> 1; };
    while (base(pi + 1) <= t2) ++pi;
    while (base(pi) > t2) --pi;
    int pj = pi + (t2 - base(pi));

    // stage panel(s): 32KB contiguous each; 256 thr x 16B = 4KB per issue
    const char* gA = (const char*)(XT + (size_t)pi * 2048);
    char* lb = (char*)lds;
    #pragma unroll
    for (int it = 0; it < 8; ++it)
        gld16(gA + it * 4096 + tid * 16, lb + it * 4096 + tid * 16);
    if (pj != pi) {
        const char* gB = (const char*)(XT + (size_t)pj * 2048);
        #pragma unroll
        for (int it = 0; it < 8; ++it)
            gld16(gB + it * 4096 + tid * 16, lb + 32768 + it * 4096 + tid * 16);
    }
    const uint4* As = lds + wm * 1024;                               // 64-row half
    const uint4* Bs = ((pj != pi) ? lds + 2048 : lds) + wn * 1024;
    const int ti = pi * 2 + wm, tj = pj * 2 + wn;                    // 64-row tiles
    __syncthreads();   // drains vmcnt (global_load_lds) before ds_reads

    float4v acc[4][4];
    #pragma unroll
    for (int mt = 0; mt < 4; ++mt)
        #pragma unroll
        for (int nt = 0; nt < 4; ++nt)
            acc[mt][nt] = (float4v){0.f, 0.f, 0.f, 0.f};

    #pragma unroll
    for (int kc = 0; kc < 4; ++kc) {
        short8 af[4], bf[4];
        #pragma unroll
        for (int mt = 0; mt < 4; ++mt)
            af[mt] = *(const short8*)&As[mt * 256 + kc * 64 + lane];
        #pragma unroll
        for (int nt = 0; nt < 4; ++nt)
            bf[nt] = *(const short8*)&Bs[nt * 256 + kc * 64 + lane];
        #pragma unroll
        for (int mt = 0; mt < 4; ++mt)
            #pragma unroll
            for (int nt = 0; nt < 4; ++nt)
                acc[mt][nt] = __builtin_amdgcn_mfma_f32_16x16x32_bf16(af[mt], bf[nt], acc[mt][nt], 0, 0, 0);
    }

    // epilogue: e = exp2(pk_fma(d, -2c4, rA*c4 + rB*c4)); sum e^{1,2,4,8,16}
    const float* rsqA = rowsq + ti * 64;
    const float* rsqB = rowsq + tj * 64;
    const float cm2 = -2.f * c4;
    const float2v cm2v = {cm2, cm2};
    float2v part2 = {0.f, 0.f};
    #pragma unroll
    for (int mt = 0; mt < 4; ++mt) {
        const float2v rA01 = { rsqA[mt * 16 + quad * 4 + 0] * c4,
                               rsqA[mt * 16 + quad * 4 + 1] * c4 };
        const float2v rA23 = { rsqA[mt * 16 + quad * 4 + 2] * c4,
                               rsqA[mt * 16 + quad * 4 + 3] * c4 };
        #pragma unroll
        for (int nt = 0; nt < 4; ++nt) {
            float rBc = rsqB[nt * 16 + mrow] * c4;
            const float2v rB2 = {rBc, rBc};
            float4v d = acc[mt][nt];
            float2v d01 = {d[0], d[1]}, d23 = {d[2], d[3]};
            float2v a01 = d01 * cm2v + (rA01 + rB2);   // v_pk_fma + v_pk_add
            float2v a23 = d23 * cm2v + (rA23 + rB2);
            float2v e1a = { __builtin_amdgcn_exp2f(a01[0]), __builtin_amdgcn_exp2f(a01[1]) };
            float2v e1b = { __builtin_amdgcn_exp2f(a23[0]), __builtin_amdgcn_exp2f(a23[1]) };
            float2v e2a = e1a * e1a, e4a = e2a * e2a, e8a = e4a * e4a, e16a = e8a * e8a;
            float2v e2b = e1b * e1b, e4b = e2b * e2b, e8b = e4b * e4b, e16b = e8b * e8b;
            part2 += (e1a + e2a) + ((e4a + e8a) + e16a);
            part2 += (e1b + e2b) + ((e4b + e8b) + e16b);
        }
    }
    float part = part2[0] + part2[1];
    #pragma unroll
    for (int off = 32; off; off >>= 1) part += __shfl_down(part, off);

    if (lane == 0) {
        float wgt;
        if (pi == pj) {
            if (wm == 1 && wn == 0) wgt = 0.f;        // duplicate quadrant
            else wgt = (ti == tj) ? 1.f : 2.f;
        } else {
            wgt = ((pi < 32) == (pj < 32)) ? 2.f : -2.f;
        }
        fpart[wv] = wgt * part;
    }
    __syncthreads();
    if (tid == 0) {
        double bs = ((double)fpart[0] + fpart[1]) + ((double)fpart[2] + fpart[3]);
        atomicAdd((double*)(wsf + 192) + (b & 31), bs);   // fire-and-forget, 65/slot
    }
}

// ---- F: one wave reduces the 32 f64 slots (proven round-5 version) ----
__global__ __launch_bounds__(64) void f_final(const float* __restrict__ wsf,
                                              float* __restrict__ out) {
    const int lane = threadIdx.x;
    const double* a = (const double*)(wsf + 192);
    double v = (lane < 32) ? a[lane] : 0.0;
    #pragma unroll
    for (int off = 32; off; off >>= 1) v += __shfl_down(v, off);
    if (lane == 0) out[0] = (float)(v * (1.0 / (4096.0 * 4096.0)));
}

extern "C" void kernel_launch(void* const* d_in, const int* in_sizes, int n_in,
                              void* d_out, int out_size, void* d_ws, size_t ws_size,
                              hipStream_t stream) {
    const float* src = (const float*)d_in[0];
    const float* tgt = (const float*)d_in[1];
    float* wsf = (float*)d_ws;
    unsigned int* XTu = (unsigned int*)(wsf + 65536);   // byte 256K, 2 MB tiled bf16

    hipMemsetAsync(wsf, 0, 1024, stream);   // ss32 + colsum + acc32
    hipLaunchKernelGGL(k_prep, dim3(2176), dim3(256), 0, stream, src, tgt, wsf, XTu);
    hipLaunchKernelGGL(mmd_main, dim3(NT2), dim3(256), 0, stream,
                       (const uint4*)XTu, wsf);
    hipLaunchKernelGGL(f_final, dim3(1), dim3(64), 0, stream, wsf, (float*)d_out);
}

// Round 8
// 92.707 us; speedup vs baseline: 1.1357x; 1.1010x over previous
//
#include <hip/hip_runtime.h>

#define D 128
#define NT2 2080            // 64*65/2 upper-triangular 128x128 super-tiles
#define NPART 8320          // NT2 * 4 quadrant partials

typedef __attribute__((ext_vector_type(8))) short short8;   // 8 x bf16 (4 VGPRs)
typedef __attribute__((ext_vector_type(4))) float float4v;  // 4 x f32 acc
typedef __attribute__((ext_vector_type(2))) float float2v;  // 2 x f32 (v_pk_* ops)

static __device__ __forceinline__ unsigned short f2bf(float f) {
    unsigned int u = __float_as_uint(f);
    unsigned int r = (u + 0x7fffu + ((u >> 16) & 1u)) >> 16;  // RNE
    return (unsigned short)r;
}

// async global->LDS, 16B per lane; lds dest must be wave-uniform base + lane*16
static __device__ __forceinline__ void gld16(const void* g, void* l) {
    __builtin_amdgcn_global_load_lds(
        (const __attribute__((address_space(1))) unsigned int*)g,
        (__attribute__((address_space(3))) unsigned int*)l, 16, 0, 0);
}

// ws float-index layout (plain stores only, nothing needs zeroing):
//   [4]              c4                   (p3_consts)
//   [512..16895]     colpart[128*128]     (k_prep colpart section)
//   [33280..41471]   rowsq[8192]          (k_prep convert section)
//   [41472..49791]   partial[8320]        (mmd, one per 64x64 quadrant)
//   [65536..]        XT: bf16 X, FRAGMENT-MAJOR tiled (2 MB)
//                    8-bf16 chunk c of row r -> uint4 idx (r>>4)*256 + c*16 + (r&15)
//                    => a 128-row super-panel p is 32KB contiguous at uint4 idx p*2048

// ---- P1+P2 fused in one dispatch (proven R2 version: plain stores, no atomics)
__global__ __launch_bounds__(256) void k_prep(const float* __restrict__ src,
                                              const float* __restrict__ tgt,
                                              float* __restrict__ wsf,
                                              unsigned int* __restrict__ XTu) {
    if (blockIdx.x < 2048) {
        float* rowsq = wsf + 33280;
        const int wv = threadIdx.x >> 6, lane = threadIdx.x & 63;
        const int gr = blockIdx.x * 4 + wv;
        const float* Xr = (gr < 4096) ? src + (size_t)gr * D : tgt + (size_t)(gr - 4096) * D;
        float2 f = ((const float2*)Xr)[lane];
        XTu[(gr >> 4) * 1024 + (lane >> 2) * 64 + (gr & 15) * 4 + (lane & 3)] =
            (unsigned)f2bf(f.x) | ((unsigned)f2bf(f.y) << 16);
        float s = f.x * f.x + f.y * f.y;
        #pragma unroll
        for (int off = 32; off; off >>= 1) s += __shfl_down(s, off);
        if (lane == 0) rowsq[gr] = s;
    } else {
        float* colpart = wsf + 512;
        int b = blockIdx.x - 2048;
        int col = threadIdx.x & 127, half = threadIdx.x >> 7;
        const float* X = (b < 64) ? src + (size_t)(b * 64) * D
                                  : tgt + (size_t)((b - 64) * 64) * D;
        float p0 = 0.f, p1 = 0.f, p2 = 0.f, p3 = 0.f;   // independent chains
        #pragma unroll 4
        for (int i = 0; i < 32; i += 4) {
            p0 += X[(size_t)(2 * (i + 0) + half) * D + col];
            p1 += X[(size_t)(2 * (i + 1) + half) * D + col];
            p2 += X[(size_t)(2 * (i + 2) + half) * D + col];
            p3 += X[(size_t)(2 * (i + 3) + half) * D + col];
        }
        __shared__ float cp[2][128];
        cp[half][col] = (p0 + p1) + (p2 + p3);
        __syncthreads();
        if (threadIdx.x < 128)
            colpart[b * 128 + threadIdx.x] = cp[0][threadIdx.x] + cp[1][threadIdx.x];
    }
}

// ---- P3: reduce -> bandwidth constant c4 (1 block, latency-tolerant; ~2 us) ----
__global__ __launch_bounds__(256) void p3_consts(float* __restrict__ wsf) {
    const float* colpart = wsf + 512;
    const float* rowsq = wsf + 33280;
    const int tid = threadIdx.x, lane = tid & 63;

    float s0 = 0.f, s1 = 0.f, s2 = 0.f, s3 = 0.f;   // sum of rowsq (= sum of squares)
    #pragma unroll
    for (int i = 0; i < 32; i += 4) {
        s0 += rowsq[tid + 256 * (i + 0)];
        s1 += rowsq[tid + 256 * (i + 1)];
        s2 += rowsq[tid + 256 * (i + 2)];
        s3 += rowsq[tid + 256 * (i + 3)];
    }
    float s = (s0 + s1) + (s2 + s3);
    #pragma unroll
    for (int off = 32; off; off >>= 1) s += __shfl_down(s, off);
    __shared__ float red[8];
    __shared__ float csum[128];
    if (lane == 0) red[tid >> 6] = s;

    int c = tid & 127, h = tid >> 7;                 // column c, half h of the 128 blocks
    float q0 = 0.f, q1 = 0.f, q2 = 0.f, q3 = 0.f;
    #pragma unroll 4
    for (int b = 0; b < 64; b += 4) {
        q0 += colpart[(h * 64 + b + 0) * 128 + c];
        q1 += colpart[(h * 64 + b + 1) * 128 + c];
        q2 += colpart[(h * 64 + b + 2) * 128 + c];
        q3 += colpart[(h * 64 + b + 3) * 128 + c];
    }
    float cs = (q0 + q1) + (q2 + q3);
    __syncthreads();
    if (h == 0) csum[c] = cs;
    __syncthreads();
    if (h == 1) csum[c] += cs;
    __syncthreads();
    float v = (tid < 128) ? csum[tid] * csum[tid] : 0.f;
    #pragma unroll
    for (int off = 32; off; off >>= 1) v += __shfl_down(v, off);
    if (lane == 0) red[4 + (tid >> 6)] = v;
    __syncthreads();
    if (tid == 0) {
        double ss = (double)red[0] + red[1] + red[2] + red[3];
        double s2 = (double)red[4] + red[5] + red[6] + red[7];
        double sumL2 = 2.0 * 8192.0 * ss - 2.0 * s2;
        double bw = sumL2 / (8192.0 * 8192.0 - 8192.0) / 4.0;  // /KERNEL_MUL^(5/2)
        wsf[4] = (float)(-1.4426950408889634 / (bw * 16.0));   // c4
    }
}

// ---- M: round-2's proven core, single change: the 20 per-lane rowsq scalar
//      loads (and their *c4) are HOISTED above the staging barrier so their
//      ~200cy L2 latency overlaps the global_load_lds wait instead of sitting
//      exposed in the epilogue dependency chain. ----
__global__ __launch_bounds__(256) void mmd_main(const uint4* __restrict__ XT,
                                                const float* __restrict__ wsf,
                                                float* __restrict__ partial) {
    __shared__ uint4 lds[4096];   // 64 KB: A panel [0,2048), B panel [2048,4096)
    const float* rowsq = wsf + 33280;
    const int tid = threadIdx.x;
    const int lane = tid & 63, wv = tid >> 6;
    const int quad = lane >> 4, mrow = lane & 15;
    const int wm = wv >> 1, wn = wv & 1;             // quadrant of the super-tile

    // XCD-aware swizzle (2080 % 8 == 0 -> bijective): contiguous t2 chunk per XCD
    int b = blockIdx.x;
    int t2 = (b & 7) * (NT2 / 8) + (b >> 3);

    // t2 -> (pi <= pj) over 64 super-panels; base(p) = p*(129-p)/2
    int pi = (int)((129.0 - sqrt(129.0 * 129.0 - 8.0 * (double)t2)) * 0.5);
    auto base = [](int p) { return (p * (129 - p)) >> 1; };
    while (base(pi + 1) <= t2) ++pi;
    while (base(pi) > t2) --pi;
    int pj = pi + (t2 - base(pi));

    // stage panel(s): 32KB contiguous each; 256 thr x 16B = 4KB per issue
    const char* gA = (const char*)(XT + (size_t)pi * 2048);
    char* lb = (char*)lds;
    #pragma unroll
    for (int it = 0; it < 8; ++it)
        gld16(gA + it * 4096 + tid * 16, lb + it * 4096 + tid * 16);
    if (pj != pi) {
        const char* gB = (const char*)(XT + (size_t)pj * 2048);
        #pragma unroll
        for (int it = 0; it < 8; ++it)
            gld16(gB + it * 4096 + tid * 16, lb + 32768 + it * 4096 + tid * 16);
    }
    const uint4* As = lds + wm * 1024;                               // 64-row half
    const uint4* Bs = ((pj != pi) ? lds + 2048 : lds) + wn * 1024;
    const int ti = pi * 2 + wm, tj = pj * 2 + wn;                    // 64-row tiles
    float c4 = wsf[4];

    // HOISTED epilogue scalars: overlap their latency with the staging wait
    const float* rsqA = rowsq + ti * 64;
    const float* rsqB = rowsq + tj * 64;
    float rAc[4][4], rBc[4];
    #pragma unroll
    for (int mt = 0; mt < 4; ++mt)
        #pragma unroll
        for (int r = 0; r < 4; ++r)
            rAc[mt][r] = rsqA[mt * 16 + quad * 4 + r] * c4;
    #pragma unroll
    for (int nt = 0; nt < 4; ++nt)
        rBc[nt] = rsqB[nt * 16 + mrow] * c4;

    __syncthreads();   // drains vmcnt (global_load_lds) before ds_reads

    float4v acc[4][4];
    #pragma unroll
    for (int mt = 0; mt < 4; ++mt)
        #pragma unroll
        for (int nt = 0; nt < 4; ++nt)
            acc[mt][nt] = (float4v){0.f, 0.f, 0.f, 0.f};

    #pragma unroll
    for (int kc = 0; kc < 4; ++kc) {
        short8 af[4], bf[4];
        #pragma unroll
        for (int mt = 0; mt < 4; ++mt)
            af[mt] = *(const short8*)&As[mt * 256 + kc * 64 + lane];
        #pragma unroll
        for (int nt = 0; nt < 4; ++nt)
            bf[nt] = *(const short8*)&Bs[nt * 256 + kc * 64 + lane];
        #pragma unroll
        for (int mt = 0; mt < 4; ++mt)
            #pragma unroll
            for (int nt = 0; nt < 4; ++nt)
                acc[mt][nt] = __builtin_amdgcn_mfma_f32_16x16x32_bf16(af[mt], bf[nt], acc[mt][nt], 0, 0, 0);
    }

    // epilogue: e = exp2(pk_fma(d, -2*c4, rAc + rBc)); sum e^{1,2,4,8,16}
    const float cm2 = -2.f * c4;
    const float2v cm2v = {cm2, cm2};
    float2v part2 = {0.f, 0.f};
    #pragma unroll
    for (int mt = 0; mt < 4; ++mt) {
        const float2v rA01 = { rAc[mt][0], rAc[mt][1] };
        const float2v rA23 = { rAc[mt][2], rAc[mt][3] };
        #pragma unroll
        for (int nt = 0; nt < 4; ++nt) {
            const float2v rB2 = {rBc[nt], rBc[nt]};
            float4v d = acc[mt][nt];
            float2v d01 = {d[0], d[1]}, d23 = {d[2], d[3]};
            float2v a01 = d01 * cm2v + (rA01 + rB2);   // v_pk_fma + v_pk_add
            float2v a23 = d23 * cm2v + (rA23 + rB2);
            float2v e1a = { __builtin_amdgcn_exp2f(a01[0]), __builtin_amdgcn_exp2f(a01[1]) };
            float2v e1b = { __builtin_amdgcn_exp2f(a23[0]), __builtin_amdgcn_exp2f(a23[1]) };
            float2v e2a = e1a * e1a, e4a = e2a * e2a, e8a = e4a * e4a, e16a = e8a * e8a;
            float2v e2b = e1b * e1b, e4b = e2b * e2b, e8b = e4b * e4b, e16b = e8b * e8b;
            part2 += (e1a + e2a) + ((e4a + e8a) + e16a);
            part2 += (e1b + e2b) + ((e4b + e8b) + e16b);
        }
    }
    float part = part2[0] + part2[1];
    #pragma unroll
    for (int off = 32; off; off >>= 1) part += __shfl_down(part, off);

    if (lane == 0) {
        float wgt;
        if (pi == pj) {
            // lower-left quadrant duplicates upper-right: weight 0 (still written:
            // poisoned ws requires every partial slot to be stored)
            if (wm == 1 && wn == 0) wgt = 0.f;
            else wgt = (ti == tj) ? 1.f : 2.f;       // same class -> sign +1
        } else {
            wgt = ((pi < 32) == (pj < 32)) ? 2.f : -2.f;
        }
        partial[t2 * 4 + wv] = wgt * part;
    }
}

// ---- F: reduce per-quadrant partials in fp64 (independent chains), scale, emit ----
__global__ __launch_bounds__(256) void f_final(const float* __restrict__ wsf,
                                               float* __restrict__ out) {
    const float* partial = wsf + 41472;
    int tid = threadIdx.x, lane = tid & 63;
    double a0 = 0.0, a1 = 0.0, a2 = 0.0, a3 = 0.0;
    #pragma unroll 4
    for (int i = tid; i < NPART; i += 1024) {
        a0 += (double)partial[i];
        if (i + 256 < NPART) a1 += (double)partial[i + 256];
        if (i + 512 < NPART) a2 += (double)partial[i + 512];
        if (i + 768 < NPART) a3 += (double)partial[i + 768];
    }
    double s = (a0 + a1) + (a2 + a3);
    #pragma unroll
    for (int off = 32; off; off >>= 1) s += __shfl_down(s, off);
    __shared__ double r4[4];
    if (lane == 0) r4[tid >> 6] = s;
    __syncthreads();
    if (tid == 0)
        out[0] = (float)(((r4[0] + r4[1]) + (r4[2] + r4[3])) * (1.0 / (4096.0 * 4096.0)));
}

extern "C" void kernel_launch(void* const* d_in, const int* in_sizes, int n_in,
                              void* d_out, int out_size, void* d_ws, size_t ws_size,
                              hipStream_t stream) {
    const float* src = (const float*)d_in[0];
    const float* tgt = (const float*)d_in[1];
    float* wsf = (float*)d_ws;
    unsigned int* XTu = (unsigned int*)(wsf + 65536);   // byte 256K, 2 MB tiled bf16
    float* partial = wsf + 41472;

    hipLaunchKernelGGL(k_prep, dim3(2176), dim3(256), 0, stream, src, tgt, wsf, XTu);
    hipLaunchKernelGGL(p3_consts, dim3(1), dim3(256), 0, stream, wsf);
    hipLaunchKernelGGL(mmd_main, dim3(NT2), dim3(256), 0, stream,
                       (const uint4*)XTu, wsf, partial);
    hipLaunchKernelGGL(f_final, dim3(1), dim3(256), 0, stream, wsf, (float*)d_out);
}